// Round 5
// baseline (399.360 us; speedup 1.0000x reference)
//
#include <hip/hip_runtime.h>
#include <stdint.h>

typedef __attribute__((ext_vector_type(4))) float  f32x4;
typedef __attribute__((ext_vector_type(8))) __bf16 bf16x8;

constexpr int F_DIM = 128;   // feature dim
constexpr int KC    = 256;   // number of centers
// u = max(sq, 1e-24)^(-1/(M-1)),  M = 1.7  ->  exponent on sq is -1/0.7
constexpr float ALPHA = -1.4285714285714286f;

__global__ __launch_bounds__(512, 4) void fcm_kernel(
        const float* __restrict__ x,
        const float* __restrict__ centers,
        float* __restrict__ out,
        int ntiles)
{
    // swizzled bf16 centers: row j, 16B chunk kc at byte j*256 + ((kc*16) ^ ((j&7)<<4))
    __shared__ __align__(16) unsigned char sB[KC * F_DIM * 2]; // 64 KiB
    __shared__ float sC2[KC];

    const int tid  = threadIdx.x;
    const int lane = tid & 63;
    const int wave = tid >> 6;

    // ---------- stage centers ONCE -> LDS (bf16, swizzled) + c2 (fp32 exact) ----------
    {
        const int j = tid >> 1;      // center index 0..255
        const int h = tid & 1;       // which half of the 128 features
        const float* src = centers + j * F_DIM + h * 64;
        float ss = 0.f;
        #pragma unroll
        for (int c = 0; c < 8; ++c) {
            f32x4 a = *(const f32x4*)(src + c * 8);
            f32x4 b = *(const f32x4*)(src + c * 8 + 4);
            ss += a.x*a.x + a.y*a.y + a.z*a.z + a.w*a.w;
            ss += b.x*b.x + b.y*b.y + b.z*b.z + b.w*b.w;
            union { __bf16 bh[8]; uint4 u4; } pk;
            pk.bh[0] = (__bf16)a.x; pk.bh[1] = (__bf16)a.y;
            pk.bh[2] = (__bf16)a.z; pk.bh[3] = (__bf16)a.w;
            pk.bh[4] = (__bf16)b.x; pk.bh[5] = (__bf16)b.y;
            pk.bh[6] = (__bf16)b.z; pk.bh[7] = (__bf16)b.w;
            const int kchunk = h * 8 + c;                       // 0..15
            const int off = j * 256 + ((kchunk * 16) ^ ((j & 7) << 4));
            *(uint4*)(sB + off) = pk.u4;
        }
        // pair-reduce the two half-row sums (lanes 2j, 2j+1 are adjacent)
        ss += __shfl_xor(ss, 1);
        if (h == 0) sC2[j] = ss;
    }
    __syncthreads();
    // centers are read-only from here on: NO barriers in the tile loop, so the
    // 16 resident waves/CU drift apart and keep a continuous HBM request mix.

    const int lrow = lane & 15;        // x-row within the wave's 16-row tile
    const int kq   = lane >> 4;        // k-quarter 0..3
    const int sw   = (lrow & 7) << 4;  // LDS swizzle for this lane's center rows

    for (int tile = blockIdx.x; tile < ntiles; tile += gridDim.x) {
        const int rbase = tile * 128 + wave * 16;
        const float* xrow = x + (long long)(rbase + lrow) * F_DIM + kq * 8;

        // ---------- load x fragments (16 rows per wave) + exact fp32 x2 ----------
        bf16x8 fragX[4];
        float x2 = 0.f;
        #pragma unroll
        for (int kb = 0; kb < 4; ++kb) {
            f32x4 a = *(const f32x4*)(xrow + kb * 32);
            f32x4 b = *(const f32x4*)(xrow + kb * 32 + 4);
            x2 += a.x*a.x + a.y*a.y + a.z*a.z + a.w*a.w;
            x2 += b.x*b.x + b.y*b.y + b.z*b.z + b.w*b.w;
            union { __bf16 bh[8]; bf16x8 v; } pk;
            pk.bh[0] = (__bf16)a.x; pk.bh[1] = (__bf16)a.y;
            pk.bh[2] = (__bf16)a.z; pk.bh[3] = (__bf16)a.w;
            pk.bh[4] = (__bf16)b.x; pk.bh[5] = (__bf16)b.y;
            pk.bh[6] = (__bf16)b.z; pk.bh[7] = (__bf16)b.w;
            fragX[kb] = pk.v;
        }
        // lanes {l, l^16, l^32, l^48} hold disjoint k-quarters of row (lane&15)
        x2 += __shfl_xor(x2, 16);
        x2 += __shfl_xor(x2, 32);

        // ---------- MFMA: D[j_center][i_xrow], A = centers (LDS), B = x (regs) ----
        // C/D layout: col = lane&15 -> x-row; row = kq*4 + r -> center within tile.
        f32x4 acc[16];
        #pragma unroll
        for (int nt = 0; nt < 16; ++nt) acc[nt] = f32x4{0.f, 0.f, 0.f, 0.f};

        #pragma unroll
        for (int nt = 0; nt < 16; ++nt) {
            const unsigned char* brow = sB + nt * 4096 + lrow * 256;
            #pragma unroll
            for (int kb = 0; kb < 4; ++kb) {
                bf16x8 fc = *(const bf16x8*)(brow + ((kb * 64 + kq * 16) ^ sw));
                acc[nt] = __builtin_amdgcn_mfma_f32_16x16x32_bf16(fc, fragX[kb], acc[nt], 0, 0, 0);
            }
        }

        // ---------- epilogue: sq -> u = sq^ALPHA, row-normalize, dwordx4 store ----
        float rowsum = 0.f;
        #pragma unroll
        for (int nt = 0; nt < 16; ++nt) {
            f32x4 c2v = *(const f32x4*)(sC2 + nt * 16 + kq * 4);
            #pragma unroll
            for (int r = 0; r < 4; ++r) {
                float sq = fmaxf(x2 + c2v[r] - 2.0f * acc[nt][r], 1e-24f);
                float u  = __builtin_amdgcn_exp2f(ALPHA * __builtin_amdgcn_logf(sq));
                acc[nt][r] = u;
                rowsum += u;
            }
        }
        // lanes l, l^16, l^32, l^48 hold disjoint center-subsets of the same x-row
        rowsum += __shfl_xor(rowsum, 16);
        rowsum += __shfl_xor(rowsum, 32);
        const float rinv = __builtin_amdgcn_rcpf(rowsum);

        float* orow = out + (long long)(rbase + lrow) * KC + kq * 4;
        #pragma unroll
        for (int nt = 0; nt < 16; ++nt) {
            f32x4 v = acc[nt] * rinv;
            *(f32x4*)(orow + nt * 16) = v;   // plain cached store: L2 merges 64B halves
        }
    }
}

extern "C" void kernel_launch(void* const* d_in, const int* in_sizes, int n_in,
                              void* d_out, int out_size, void* d_ws, size_t ws_size,
                              hipStream_t stream) {
    const float* x       = (const float*)d_in[0];
    const float* centers = (const float*)d_in[1];
    float* out           = (float*)d_out;

    const int N      = in_sizes[0] / F_DIM;   // 262144
    const int ntiles = N / 128;               // 2048 tiles of 128 rows
    const int blocks = 512;                   // persistent: 2 blocks/CU on 256 CUs
    fcm_kernel<<<blocks, 512, 0, stream>>>(x, centers, out, ntiles);
}

// Round 6
// 97.046 us; speedup vs baseline: 4.1152x; 4.1152x over previous
//
#include <hip/hip_runtime.h>
#include <stdint.h>

typedef __attribute__((ext_vector_type(4))) float  f32x4;
typedef __attribute__((ext_vector_type(8))) __bf16 bf16x8;

typedef __attribute__((address_space(1))) const unsigned int g_u32;
typedef __attribute__((address_space(3))) unsigned int       l_u32;

constexpr int F_DIM = 128;   // feature dim
constexpr int KC    = 256;   // number of centers
// u = max(sq, 1e-24)^(-1/(M-1)),  M = 1.7  ->  exponent on sq is -1/0.7
constexpr float ALPHA = -1.4285714285714286f;

// ---------------------------------------------------------------------------
// Pre-kernel: centers (fp32, row-major) -> d_ws as {pre-swizzled bf16 image
// (64 KiB), c2 table (1 KiB)}. Runs once per launch; L3/L2-resident after.
// Swizzle: row j, 16B chunk kc lives at byte j*256 + ((kc*16) ^ ((j&7)<<4)).
// ---------------------------------------------------------------------------
__global__ __launch_bounds__(64) void fcm_prep(
        const float* __restrict__ centers,
        unsigned char* __restrict__ wsB,
        float* __restrict__ wsC2)
{
    const int j    = blockIdx.x;     // center 0..255
    const int lane = threadIdx.x;    // 0..63, handles elements 2*lane, 2*lane+1
    const float2 v = *(const float2*)(centers + j * F_DIM + 2 * lane);
    union { __bf16 h[2]; unsigned int u; } pk;
    pk.h[0] = (__bf16)v.x; pk.h[1] = (__bf16)v.y;
    const int kc  = lane >> 2;       // 16B chunk 0..15
    const int off = j * 256 + (((kc * 16) ^ ((j & 7) << 4)) | ((lane & 3) * 4));
    *(unsigned int*)(wsB + off) = pk.u;

    float ss = v.x * v.x + v.y * v.y;
    ss += __shfl_xor(ss, 1);  ss += __shfl_xor(ss, 2);  ss += __shfl_xor(ss, 4);
    ss += __shfl_xor(ss, 8);  ss += __shfl_xor(ss, 16); ss += __shfl_xor(ss, 32);
    if (lane == 0) wsC2[j] = ss;
}

// ---------------------------------------------------------------------------
// Main kernel: R4 structure; staging replaced by async global_load_lds DMA
// of the pre-swizzled image (zero VALU, overlapped with x load+convert).
// ---------------------------------------------------------------------------
__global__ __launch_bounds__(512, 4) void fcm_kernel(
        const float* __restrict__ x,
        const unsigned char* __restrict__ wsB,
        const float* __restrict__ wsC2,
        float* __restrict__ out)
{
    __shared__ __align__(16) unsigned char sB[KC * F_DIM * 2]; // 64 KiB
    __shared__ float sC2[KC];

    const int tid  = threadIdx.x;
    const int lane = tid & 63;
    const int wave = tid >> 6;

    // ---------- async-stage pre-swizzled centers + c2 (identity copy) ----------
    #pragma unroll
    for (int i = 0; i < 8; ++i) {
        const unsigned char* gsrc = wsB + wave * 1024 + i * 8192 + lane * 16;
        unsigned char*       ldst = sB  + wave * 1024 + i * 8192;
        __builtin_amdgcn_global_load_lds((g_u32*)gsrc, (l_u32*)ldst, 16, 0, 0);
    }
    if (wave < 4) {
        __builtin_amdgcn_global_load_lds((g_u32*)(wsC2 + wave * 64 + lane),
                                         (l_u32*)(sC2 + wave * 64), 4, 0, 0);
    }

    // ---------- x fragments (16 rows/wave) + exact fp32 x2, while DMA flies ----
    const int rbase = blockIdx.x * 128 + wave * 16;
    const int lrow  = lane & 15;   // x-row within the wave's 16-row tile
    const int kq    = lane >> 4;   // k-quarter 0..3
    const float* xrow = x + (long long)(rbase + lrow) * F_DIM + kq * 8;

    bf16x8 fragX[4];
    float x2 = 0.f;
    #pragma unroll
    for (int kb = 0; kb < 4; ++kb) {
        f32x4 a = *(const f32x4*)(xrow + kb * 32);
        f32x4 b = *(const f32x4*)(xrow + kb * 32 + 4);
        x2 += a.x*a.x + a.y*a.y + a.z*a.z + a.w*a.w;
        x2 += b.x*b.x + b.y*b.y + b.z*b.z + b.w*b.w;
        union { __bf16 bh[8]; bf16x8 v; } pk;
        pk.bh[0] = (__bf16)a.x; pk.bh[1] = (__bf16)a.y;
        pk.bh[2] = (__bf16)a.z; pk.bh[3] = (__bf16)a.w;
        pk.bh[4] = (__bf16)b.x; pk.bh[5] = (__bf16)b.y;
        pk.bh[6] = (__bf16)b.z; pk.bh[7] = (__bf16)b.w;
        fragX[kb] = pk.v;
    }
    // lanes {l, l^16, l^32, l^48} hold disjoint k-quarters of row (lane&15)
    x2 += __shfl_xor(x2, 16);
    x2 += __shfl_xor(x2, 32);
    // every lane now holds ||x_row||^2 for its row (lane&15)

    __syncthreads();   // compiler drains vmcnt(0) here: DMA staging complete

    // ---------- MFMA: D[j_center][i_xrow], A = centers (LDS), B = x (regs) ----
    // C/D layout: col = lane&15 -> x-row; row = kq*4 + r -> center within tile.
    f32x4 acc[16];
    #pragma unroll
    for (int nt = 0; nt < 16; ++nt) acc[nt] = f32x4{0.f, 0.f, 0.f, 0.f};

    const int sw = (lrow & 7) << 4;   // j = nt*16+lrow -> j&7 == lrow&7
    #pragma unroll
    for (int nt = 0; nt < 16; ++nt) {
        const unsigned char* brow = sB + nt * 4096 + lrow * 256;
        #pragma unroll
        for (int kb = 0; kb < 4; ++kb) {
            bf16x8 fc = *(const bf16x8*)(brow + ((kb * 64 + kq * 16) ^ sw));
            acc[nt] = __builtin_amdgcn_mfma_f32_16x16x32_bf16(fc, fragX[kb], acc[nt], 0, 0, 0);
        }
    }

    // ---------- epilogue: sq -> u = sq^ALPHA, row-normalize, dwordx4 store ----
    float rowsum = 0.f;
    #pragma unroll
    for (int nt = 0; nt < 16; ++nt) {
        f32x4 c2v = *(const f32x4*)(sC2 + nt * 16 + kq * 4);
        #pragma unroll
        for (int r = 0; r < 4; ++r) {
            float sq = fmaxf(x2 + c2v[r] - 2.0f * acc[nt][r], 1e-24f);
            float u  = __builtin_amdgcn_exp2f(ALPHA * __builtin_amdgcn_logf(sq));
            acc[nt][r] = u;
            rowsum += u;
        }
    }
    // lanes l, l^16, l^32, l^48 hold disjoint center-subsets of the same x-row
    rowsum += __shfl_xor(rowsum, 16);
    rowsum += __shfl_xor(rowsum, 32);
    const float rinv = __builtin_amdgcn_rcpf(rowsum);

    float* orow = out + (long long)(rbase + lrow) * KC + kq * 4;
    #pragma unroll
    for (int nt = 0; nt < 16; ++nt) {
        f32x4 v = acc[nt] * rinv;
        *(f32x4*)(orow + nt * 16) = v;
    }
}

extern "C" void kernel_launch(void* const* d_in, const int* in_sizes, int n_in,
                              void* d_out, int out_size, void* d_ws, size_t ws_size,
                              hipStream_t stream) {
    const float* x       = (const float*)d_in[0];
    const float* centers = (const float*)d_in[1];
    float* out           = (float*)d_out;

    unsigned char* wsB  = (unsigned char*)d_ws;          // 64 KiB bf16 swizzled
    float*         wsC2 = (float*)(wsB + KC * F_DIM * 2); // 1 KiB c2 table

    const int N      = in_sizes[0] / F_DIM;   // 262144
    const int blocks = N / 128;               // 2048 blocks of 128 rows

    fcm_prep<<<KC, 64, 0, stream>>>(centers, wsB, wsC2);
    fcm_kernel<<<blocks, 512, 0, stream>>>(x, wsB, wsC2, out);
}